// Round 2
// baseline (951.638 us; speedup 1.0000x reference)
//
#include <hip/hip_runtime.h>
#include <stdint.h>

// Trilinear resampler, REPLICATE (clamp) boundary, locality-sorted.
// inputs:  [B, D, H, W, C] fp32   (B=2, D=H=W=128, C=8)
// coords:  [B, GD, GH, GW, 3] fp32, order (d, h, w)
// output:  [B, GD, GH, GW, C] fp32

constexpr int B  = 2;
constexpr int D  = 128;
constexpr int H  = 128;
constexpr int W  = 128;
constexpr int C  = 8;
constexpr int GD = 96;
constexpr int GH = 96;
constexpr int GW = 96;
constexpr long long PTS_PER_B = (long long)GD * GH * GW;   // 884736
constexpr long long NPTS      = (long long)B * PTS_PER_B;  // 1769472

constexpr int TILE_SHIFT = 4;                 // 16^3 voxel tiles
constexpr int TPD = D >> TILE_SHIFT;          // 8 tiles per dim
constexpr int NT_PER_B = TPD * TPD * TPD;     // 512
constexpr int NT = B * NT_PER_B;              // 1024 buckets

__device__ __forceinline__ int clampi(int v, int lo, int hi) {
    return min(max(v, lo), hi);
}

__device__ __forceinline__ int tile_of(int b, float zc, float yc, float xc) {
    int z0 = clampi((int)floorf(zc), 0, D - 1);
    int y0 = clampi((int)floorf(yc), 0, H - 1);
    int x0 = clampi((int)floorf(xc), 0, W - 1);
    int tz = z0 >> TILE_SHIFT, ty = y0 >> TILE_SHIFT, tx = x0 >> TILE_SHIFT;
    return ((b * TPD + tz) * TPD + ty) * TPD + tx;
}

// ---- K1: histogram ---------------------------------------------------------
__global__ __launch_bounds__(256)
void k_hist(const float* __restrict__ coords, uint32_t* __restrict__ counts)
{
    long long i = (long long)blockIdx.x * blockDim.x + threadIdx.x;
    if (i >= NPTS) return;
    int b = (int)(i / PTS_PER_B);
    float zc = coords[3 * i + 0];
    float yc = coords[3 * i + 1];
    float xc = coords[3 * i + 2];
    atomicAdd(&counts[tile_of(b, zc, yc, xc)], 1u);
}

// ---- K2: exclusive scan over NT=1024 entries (one block) -------------------
__global__ __launch_bounds__(1024)
void k_scan(const uint32_t* __restrict__ counts, uint32_t* __restrict__ cursors)
{
    __shared__ uint32_t s[NT];
    int t = threadIdx.x;
    uint32_t my = counts[t];
    s[t] = my;
    __syncthreads();
    // Hillis-Steele inclusive scan
    for (int off = 1; off < NT; off <<= 1) {
        uint32_t v = (t >= off) ? s[t - off] : 0u;
        __syncthreads();
        s[t] += v;
        __syncthreads();
    }
    cursors[t] = s[t] - my;   // exclusive
}

// ---- K3: scatter records into bucket order ---------------------------------
__global__ __launch_bounds__(256)
void k_scatter(const float* __restrict__ coords, uint32_t* __restrict__ cursors,
               float4* __restrict__ records)
{
    long long i = (long long)blockIdx.x * blockDim.x + threadIdx.x;
    if (i >= NPTS) return;
    int b = (int)(i / PTS_PER_B);
    float zc = coords[3 * i + 0];
    float yc = coords[3 * i + 1];
    float xc = coords[3 * i + 2];
    int t = tile_of(b, zc, yc, xc);
    uint32_t slot = atomicAdd(&cursors[t], 1u);
    records[slot] = make_float4(zc, yc, xc, __uint_as_float((uint32_t)i));
}

// ---- K4: trilinear sample on sorted records --------------------------------
__global__ __launch_bounds__(256)
void k_sample(const float* __restrict__ inp, const float4* __restrict__ records,
              float* __restrict__ out, int nblk)
{
    // XCD-chunked swizzle: consecutive chunks of the sorted array (same
    // bucket) land on the SAME XCD so its L2 fetches each 16^3 region once.
    int g = blockIdx.x;
    int cpx = nblk >> 3;                       // nblk % 8 == 0 by construction
    int chunk = (g & 7) * cpx + (g >> 3);
    long long i = (long long)chunk * blockDim.x + threadIdx.x;
    if (i >= NPTS) return;

    float4 rec = records[i];
    const float zc = rec.x, yc = rec.y, xc = rec.z;
    const uint32_t idx = __float_as_uint(rec.w);
    const int b = (int)(idx / (uint32_t)PTS_PER_B);

    const float fz = floorf(zc);
    const float fy = floorf(yc);
    const float fx = floorf(xc);

    float wz1 = zc - fz, wz0 = 1.0f - wz1;
    float wy1 = yc - fy, wy0 = 1.0f - wy1;
    float wx1 = xc - fx, wx0 = 1.0f - wx1;

    int z0 = clampi((int)fz, 0, D - 1);
    int y0 = clampi((int)fy, 0, H - 1);
    int x0 = clampi((int)fx, 0, W - 1);
    const int z1 = min(z0 + 1, D - 1);
    const int y1 = min(y0 + 1, H - 1);
    const int x1 = min(x0 + 1, W - 1);

    const long long bb = (long long)b * D;

    float4 acc_lo = make_float4(0.f, 0.f, 0.f, 0.f);
    float4 acc_hi = make_float4(0.f, 0.f, 0.f, 0.f);

    const int   zs[2]  = {z0, z1};
    const int   ys[2]  = {y0, y1};
    const int   xs[2]  = {x0, x1};
    const float wzs[2] = {wz0, wz1};
    const float wys[2] = {wy0, wy1};
    const float wxs[2] = {wx0, wx1};

#pragma unroll
    for (int iz = 0; iz < 2; ++iz) {
#pragma unroll
        for (int iy = 0; iy < 2; ++iy) {
#pragma unroll
            for (int ix = 0; ix < 2; ++ix) {
                const float wt = wzs[iz] * wys[iy] * wxs[ix];
                const long long base =
                    ((((bb + zs[iz]) * H + ys[iy]) * W) + xs[ix]) * (long long)C;
                const float4 v0 = *reinterpret_cast<const float4*>(inp + base);
                const float4 v1 = *reinterpret_cast<const float4*>(inp + base + 4);
                acc_lo.x += wt * v0.x;  acc_lo.y += wt * v0.y;
                acc_lo.z += wt * v0.z;  acc_lo.w += wt * v0.w;
                acc_hi.x += wt * v1.x;  acc_hi.y += wt * v1.y;
                acc_hi.z += wt * v1.z;  acc_hi.w += wt * v1.w;
            }
        }
    }

    float* o = out + (long long)idx * C;
    *reinterpret_cast<float4*>(o)     = acc_lo;
    *reinterpret_cast<float4*>(o + 4) = acc_hi;
}

// ---- fallback: round-1 direct kernel (if ws too small) ---------------------
__global__ __launch_bounds__(256)
void resample_direct(const float* __restrict__ inp,
                     const float* __restrict__ coords,
                     float* __restrict__ out)
{
    long long i = (long long)blockIdx.x * blockDim.x + threadIdx.x;
    if (i >= NPTS) return;
    int b = (int)(i / PTS_PER_B);
    const float zc = coords[3 * i + 0];
    const float yc = coords[3 * i + 1];
    const float xc = coords[3 * i + 2];
    const float fz = floorf(zc), fy = floorf(yc), fx = floorf(xc);
    float wz1 = zc - fz, wz0 = 1.0f - wz1;
    float wy1 = yc - fy, wy0 = 1.0f - wy1;
    float wx1 = xc - fx, wx0 = 1.0f - wx1;
    int z0 = clampi((int)fz, 0, D - 1);
    int y0 = clampi((int)fy, 0, H - 1);
    int x0 = clampi((int)fx, 0, W - 1);
    const int z1 = min(z0 + 1, D - 1);
    const int y1 = min(y0 + 1, H - 1);
    const int x1 = min(x0 + 1, W - 1);
    const long long bb = (long long)b * D;
    float4 acc_lo = make_float4(0.f, 0.f, 0.f, 0.f);
    float4 acc_hi = make_float4(0.f, 0.f, 0.f, 0.f);
    const int   zs[2]  = {z0, z1};
    const int   ys[2]  = {y0, y1};
    const int   xs[2]  = {x0, x1};
    const float wzs[2] = {wz0, wz1};
    const float wys[2] = {wy0, wy1};
    const float wxs[2] = {wx0, wx1};
#pragma unroll
    for (int iz = 0; iz < 2; ++iz)
#pragma unroll
        for (int iy = 0; iy < 2; ++iy)
#pragma unroll
            for (int ix = 0; ix < 2; ++ix) {
                const float wt = wzs[iz] * wys[iy] * wxs[ix];
                const long long base =
                    ((((bb + zs[iz]) * H + ys[iy]) * W) + xs[ix]) * (long long)C;
                const float4 v0 = *reinterpret_cast<const float4*>(inp + base);
                const float4 v1 = *reinterpret_cast<const float4*>(inp + base + 4);
                acc_lo.x += wt * v0.x;  acc_lo.y += wt * v0.y;
                acc_lo.z += wt * v0.z;  acc_lo.w += wt * v0.w;
                acc_hi.x += wt * v1.x;  acc_hi.y += wt * v1.y;
                acc_hi.z += wt * v1.z;  acc_hi.w += wt * v1.w;
            }
    float* o = out + i * C;
    *reinterpret_cast<float4*>(o)     = acc_lo;
    *reinterpret_cast<float4*>(o + 4) = acc_hi;
}

extern "C" void kernel_launch(void* const* d_in, const int* in_sizes, int n_in,
                              void* d_out, int out_size, void* d_ws, size_t ws_size,
                              hipStream_t stream)
{
    const float* inp    = (const float*)d_in[0];
    const float* coords = (const float*)d_in[1];
    float* out          = (float*)d_out;

    const int threads = 256;
    const int nblk = (int)((NPTS + threads - 1) / threads);   // 6912, % 8 == 0

    // ws layout: records (float4[NPTS]) | counts (u32[NT]) | cursors (u32[NT])
    const size_t rec_bytes = (size_t)NPTS * sizeof(float4);   // 28,311,552
    const size_t needed    = rec_bytes + 2 * (size_t)NT * sizeof(uint32_t);

    if (ws_size < needed) {
        resample_direct<<<nblk, threads, 0, stream>>>(inp, coords, out);
        return;
    }

    float4*   records = (float4*)d_ws;
    uint32_t* counts  = (uint32_t*)((char*)d_ws + rec_bytes);
    uint32_t* cursors = counts + NT;

    hipMemsetAsync(counts, 0, (size_t)NT * sizeof(uint32_t), stream);
    k_hist   <<<nblk, threads, 0, stream>>>(coords, counts);
    k_scan   <<<1, NT, 0, stream>>>(counts, cursors);
    k_scatter<<<nblk, threads, 0, stream>>>(coords, cursors, records);
    k_sample <<<nblk, threads, 0, stream>>>(inp, records, out, nblk);
}

// Round 3
// 135.675 us; speedup vs baseline: 7.0141x; 7.0141x over previous
//
#include <hip/hip_runtime.h>
#include <stdint.h>

// Trilinear resampler, REPLICATE (clamp) boundary, locality-sorted,
// fully global-atomic-free (deterministic two-level counting sort).
// inputs:  [B, D, H, W, C] fp32   (B=2, D=H=W=128, C=8)
// coords:  [B, GD, GH, GW, 3] fp32, order (d, h, w)
// output:  [B, GD, GH, GW, C] fp32

constexpr int B  = 2;
constexpr int D  = 128;
constexpr int H  = 128;
constexpr int W  = 128;
constexpr int C  = 8;
constexpr int GD = 96;
constexpr int GH = 96;
constexpr int GW = 96;
constexpr long long PTS_PER_B = (long long)GD * GH * GW;   // 884736
constexpr long long NPTS      = (long long)B * PTS_PER_B;  // 1769472

constexpr int TILE_SHIFT = 4;                 // 16^3 voxel tiles
constexpr int TPD = D >> TILE_SHIFT;          // 8 tiles per dim
constexpr int NT_PER_B = TPD * TPD * TPD;     // 512
constexpr int NT = B * NT_PER_B;              // 1024 buckets

constexpr int TPB_BIN = 1024;                 // threads per binning block
constexpr int PPT     = 8;                    // points per thread
constexpr int NB_BIN  = (int)(NPTS / ((long long)TPB_BIN * PPT));  // 216
static_assert((long long)NB_BIN * TPB_BIN * PPT == NPTS, "exact tiling");

__device__ __forceinline__ int clampi(int v, int lo, int hi) {
    return min(max(v, lo), hi);
}

__device__ __forceinline__ int tile_of(int b, float zc, float yc, float xc) {
    int z0 = clampi((int)floorf(zc), 0, D - 1);
    int y0 = clampi((int)floorf(yc), 0, H - 1);
    int x0 = clampi((int)floorf(xc), 0, W - 1);
    int tz = z0 >> TILE_SHIFT, ty = y0 >> TILE_SHIFT, tx = x0 >> TILE_SHIFT;
    return ((b * TPD + tz) * TPD + ty) * TPD + tx;
}

// ---- K1: per-block LDS histogram -> blockHist[block][NT] -------------------
__global__ __launch_bounds__(TPB_BIN)
void k_hist(const float* __restrict__ coords, uint32_t* __restrict__ blockHist)
{
    __shared__ uint32_t h[NT];
    const int t = threadIdx.x;
    h[t] = 0u;                       // NT == TPB_BIN
    __syncthreads();

    const long long base = (long long)blockIdx.x * (TPB_BIN * PPT);
#pragma unroll
    for (int k = 0; k < PPT; ++k) {
        const long long i = base + (long long)k * TPB_BIN + t;
        const float zc = coords[3 * i + 0];
        const float yc = coords[3 * i + 1];
        const float xc = coords[3 * i + 2];
        const int b = (int)(i / PTS_PER_B);
        atomicAdd(&h[tile_of(b, zc, yc, xc)], 1u);
    }
    __syncthreads();
    blockHist[(long long)blockIdx.x * NT + t] = h[t];
}

// ---- K2: column scan over blocks (in place) + bucket-base scan -------------
__global__ __launch_bounds__(TPB_BIN)
void k_scan(uint32_t* __restrict__ blockHist, uint32_t* __restrict__ bucketBase)
{
    __shared__ uint32_t s[NT];
    const int t = threadIdx.x;

    uint32_t acc = 0u;
#pragma unroll 8
    for (int b = 0; b < NB_BIN; ++b) {
        const long long o = (long long)b * NT + t;
        const uint32_t v = blockHist[o];
        blockHist[o] = acc;          // exclusive within-bucket prefix
        acc += v;
    }

    s[t] = acc;                      // per-bucket total
    __syncthreads();
    for (int off = 1; off < NT; off <<= 1) {
        const uint32_t v = (t >= off) ? s[t - off] : 0u;
        __syncthreads();
        s[t] += v;
        __syncthreads();
    }
    bucketBase[t] = s[t] - acc;      // exclusive bucket base
}

// ---- K3: scatter records via LDS cursors (no global atomics) ---------------
__global__ __launch_bounds__(TPB_BIN)
void k_scatter(const float* __restrict__ coords,
               const uint32_t* __restrict__ blockHist,
               const uint32_t* __restrict__ bucketBase,
               float4* __restrict__ records)
{
    __shared__ uint32_t cur[NT];
    const int t = threadIdx.x;
    cur[t] = blockHist[(long long)blockIdx.x * NT + t] + bucketBase[t];
    __syncthreads();

    const long long base = (long long)blockIdx.x * (TPB_BIN * PPT);
#pragma unroll
    for (int k = 0; k < PPT; ++k) {
        const long long i = base + (long long)k * TPB_BIN + t;
        const float zc = coords[3 * i + 0];
        const float yc = coords[3 * i + 1];
        const float xc = coords[3 * i + 2];
        const int b = (int)(i / PTS_PER_B);
        const int tk = tile_of(b, zc, yc, xc);
        const uint32_t slot = atomicAdd(&cur[tk], 1u);   // LDS atomic: fast
        records[slot] = make_float4(zc, yc, xc, __uint_as_float((uint32_t)i));
    }
}

// ---- K4: trilinear sample on sorted records --------------------------------
__global__ __launch_bounds__(256)
void k_sample(const float* __restrict__ inp, const float4* __restrict__ records,
              float* __restrict__ out, int nblk)
{
    // XCD-chunked swizzle: consecutive chunks of the sorted array (same
    // bucket) land on the SAME XCD so its L2 fetches each 16^3 region once.
    const int g = blockIdx.x;
    const int cpx = nblk >> 3;                 // nblk % 8 == 0
    const int chunk = (g & 7) * cpx + (g >> 3);
    const long long i = (long long)chunk * blockDim.x + threadIdx.x;
    if (i >= NPTS) return;

    const float4 rec = records[i];
    const float zc = rec.x, yc = rec.y, xc = rec.z;
    const uint32_t idx = __float_as_uint(rec.w);
    const int b = (int)(idx / (uint32_t)PTS_PER_B);

    const float fz = floorf(zc);
    const float fy = floorf(yc);
    const float fx = floorf(xc);

    const float wz1 = zc - fz, wz0 = 1.0f - wz1;
    const float wy1 = yc - fy, wy0 = 1.0f - wy1;
    const float wx1 = xc - fx, wx0 = 1.0f - wx1;

    const int z0 = clampi((int)fz, 0, D - 1);
    const int y0 = clampi((int)fy, 0, H - 1);
    const int x0 = clampi((int)fx, 0, W - 1);
    const int z1 = min(z0 + 1, D - 1);
    const int y1 = min(y0 + 1, H - 1);
    const int x1 = min(x0 + 1, W - 1);

    const long long bb = (long long)b * D;

    float4 acc_lo = make_float4(0.f, 0.f, 0.f, 0.f);
    float4 acc_hi = make_float4(0.f, 0.f, 0.f, 0.f);

    const int   zs[2]  = {z0, z1};
    const int   ys[2]  = {y0, y1};
    const int   xs[2]  = {x0, x1};
    const float wzs[2] = {wz0, wz1};
    const float wys[2] = {wy0, wy1};
    const float wxs[2] = {wx0, wx1};

#pragma unroll
    for (int iz = 0; iz < 2; ++iz) {
#pragma unroll
        for (int iy = 0; iy < 2; ++iy) {
#pragma unroll
            for (int ix = 0; ix < 2; ++ix) {
                const float wt = wzs[iz] * wys[iy] * wxs[ix];
                const long long base =
                    ((((bb + zs[iz]) * H + ys[iy]) * W) + xs[ix]) * (long long)C;
                const float4 v0 = *reinterpret_cast<const float4*>(inp + base);
                const float4 v1 = *reinterpret_cast<const float4*>(inp + base + 4);
                acc_lo.x += wt * v0.x;  acc_lo.y += wt * v0.y;
                acc_lo.z += wt * v0.z;  acc_lo.w += wt * v0.w;
                acc_hi.x += wt * v1.x;  acc_hi.y += wt * v1.y;
                acc_hi.z += wt * v1.z;  acc_hi.w += wt * v1.w;
            }
        }
    }

    float* o = out + (long long)idx * C;
    *reinterpret_cast<float4*>(o)     = acc_lo;
    *reinterpret_cast<float4*>(o + 4) = acc_hi;
}

// ---- fallback: direct kernel (if ws too small) -----------------------------
__global__ __launch_bounds__(256)
void resample_direct(const float* __restrict__ inp,
                     const float* __restrict__ coords,
                     float* __restrict__ out)
{
    const long long i = (long long)blockIdx.x * blockDim.x + threadIdx.x;
    if (i >= NPTS) return;
    const int b = (int)(i / PTS_PER_B);
    const float zc = coords[3 * i + 0];
    const float yc = coords[3 * i + 1];
    const float xc = coords[3 * i + 2];
    const float fz = floorf(zc), fy = floorf(yc), fx = floorf(xc);
    const float wz1 = zc - fz, wz0 = 1.0f - wz1;
    const float wy1 = yc - fy, wy0 = 1.0f - wy1;
    const float wx1 = xc - fx, wx0 = 1.0f - wx1;
    const int z0 = clampi((int)fz, 0, D - 1);
    const int y0 = clampi((int)fy, 0, H - 1);
    const int x0 = clampi((int)fx, 0, W - 1);
    const int z1 = min(z0 + 1, D - 1);
    const int y1 = min(y0 + 1, H - 1);
    const int x1 = min(x0 + 1, W - 1);
    const long long bb = (long long)b * D;
    float4 acc_lo = make_float4(0.f, 0.f, 0.f, 0.f);
    float4 acc_hi = make_float4(0.f, 0.f, 0.f, 0.f);
    const int   zs[2]  = {z0, z1};
    const int   ys[2]  = {y0, y1};
    const int   xs[2]  = {x0, x1};
    const float wzs[2] = {wz0, wz1};
    const float wys[2] = {wy0, wy1};
    const float wxs[2] = {wx0, wx1};
#pragma unroll
    for (int iz = 0; iz < 2; ++iz)
#pragma unroll
        for (int iy = 0; iy < 2; ++iy)
#pragma unroll
            for (int ix = 0; ix < 2; ++ix) {
                const float wt = wzs[iz] * wys[iy] * wxs[ix];
                const long long base =
                    ((((bb + zs[iz]) * H + ys[iy]) * W) + xs[ix]) * (long long)C;
                const float4 v0 = *reinterpret_cast<const float4*>(inp + base);
                const float4 v1 = *reinterpret_cast<const float4*>(inp + base + 4);
                acc_lo.x += wt * v0.x;  acc_lo.y += wt * v0.y;
                acc_lo.z += wt * v0.z;  acc_lo.w += wt * v0.w;
                acc_hi.x += wt * v1.x;  acc_hi.y += wt * v1.y;
                acc_hi.z += wt * v1.z;  acc_hi.w += wt * v1.w;
            }
    float* o = out + i * C;
    *reinterpret_cast<float4*>(o)     = acc_lo;
    *reinterpret_cast<float4*>(o + 4) = acc_hi;
}

extern "C" void kernel_launch(void* const* d_in, const int* in_sizes, int n_in,
                              void* d_out, int out_size, void* d_ws, size_t ws_size,
                              hipStream_t stream)
{
    const float* inp    = (const float*)d_in[0];
    const float* coords = (const float*)d_in[1];
    float* out          = (float*)d_out;

    const int threads = 256;
    const int nblk = (int)((NPTS + threads - 1) / threads);   // 6912, % 8 == 0

    // ws layout: records f4[NPTS] | blockHist u32[NB_BIN*NT] | bucketBase u32[NT]
    const size_t rec_bytes  = (size_t)NPTS * sizeof(float4);          // 28,311,552
    const size_t hist_bytes = (size_t)NB_BIN * NT * sizeof(uint32_t); //    884,736
    const size_t needed     = rec_bytes + hist_bytes + (size_t)NT * sizeof(uint32_t);

    if (ws_size < needed) {
        resample_direct<<<nblk, threads, 0, stream>>>(inp, coords, out);
        return;
    }

    float4*   records    = (float4*)d_ws;
    uint32_t* blockHist  = (uint32_t*)((char*)d_ws + rec_bytes);
    uint32_t* bucketBase = (uint32_t*)((char*)d_ws + rec_bytes + hist_bytes);

    k_hist   <<<NB_BIN, TPB_BIN, 0, stream>>>(coords, blockHist);
    k_scan   <<<1,      TPB_BIN, 0, stream>>>(blockHist, bucketBase);
    k_scatter<<<NB_BIN, TPB_BIN, 0, stream>>>(coords, blockHist, bucketBase, records);
    k_sample <<<nblk,   threads, 0, stream>>>(inp, records, out, nblk);
}